// Round 1
// baseline (608.745 us; speedup 1.0000x reference)
//
#include <hip/hip_runtime.h>
#include <math.h>

// Problem constants: x[B,T,C], Wq/Wk/Wv[H,C,D], out[B,T,H*D]
constexpr int B_ = 4, T_ = 1024, C_ = 768, H_ = 12, D_ = 64;
constexpr int BH_ = B_ * H_;  // 48

// ---------------------------------------------------------------------------
// Kernel 1: fused QKV projection GEMM.
// A = x viewed as [M=4096, K=768] row-major.
// B = per (proj p, head h): W_p[h] is [768, 64] row-major.
// N dimension = p*768 + h*64 + d (2304 cols); a 64-wide n-tile == one (p,h).
// Output layout: qkv[p][b*H+h][t][d]  (each [T,D] panel row-major) in d_ws.
// 64x64x32 block tile, 256 threads, 4x4 micro-tile each.
// ---------------------------------------------------------------------------
__global__ __launch_bounds__(256) void proj_kernel(
    const float* __restrict__ x,
    const float* __restrict__ Wq,
    const float* __restrict__ Wk,
    const float* __restrict__ Wv,
    float* __restrict__ qkv)
{
    __shared__ float As[32][68];   // transposed [k][m], pad 68 keeps float4 align + spreads banks
    __shared__ float Bs[32][64];   // [k][n]

    const int ntile = blockIdx.x;          // 0..35
    const int mtile = blockIdx.y;          // 0..63
    const int p = ntile / H_;
    const int h = ntile - p * H_;
    const float* W = (p == 0) ? Wq : (p == 1 ? Wk : Wv);
    const float* Wh = W + (size_t)h * C_ * D_;
    const int m0 = mtile * 64;
    const int tid = threadIdx.x;
    const int tr = tid >> 4, tc = tid & 15;

    float acc[4][4] = {};

    for (int k0 = 0; k0 < C_; k0 += 32) {
#pragma unroll
        for (int i = 0; i < 2; ++i) {
            int f = tid + 256 * i;         // 0..511
            // A tile: 64 rows x 32 k = 512 float4 (8 float4 per row)
            int mm = f >> 3, kg = f & 7;
            float4 a = *(const float4*)(x + (size_t)(m0 + mm) * C_ + k0 + kg * 4);
            As[kg * 4 + 0][mm] = a.x;
            As[kg * 4 + 1][mm] = a.y;
            As[kg * 4 + 2][mm] = a.z;
            As[kg * 4 + 3][mm] = a.w;
            // B tile: 32 rows x 64 d = 512 float4 (16 float4 per row)
            int kk = f >> 4, dg = f & 15;
            *(float4*)(&Bs[kk][dg * 4]) = *(const float4*)(Wh + (size_t)(k0 + kk) * D_ + dg * 4);
        }
        __syncthreads();
#pragma unroll
        for (int kk = 0; kk < 32; ++kk) {
            float4 a4 = *(const float4*)(&As[kk][tr * 4]);
            float4 b4 = *(const float4*)(&Bs[kk][tc * 4]);
            float av[4] = {a4.x, a4.y, a4.z, a4.w};
            float bv[4] = {b4.x, b4.y, b4.z, b4.w};
#pragma unroll
            for (int ii = 0; ii < 4; ++ii)
#pragma unroll
                for (int jj = 0; jj < 4; ++jj)
                    acc[ii][jj] = fmaf(av[ii], bv[jj], acc[ii][jj]);
        }
        __syncthreads();
    }

    // Write out: rows m0 + 4*tr + ir, cols d = 4*tc + jj, panel (p, b, h).
    const int bq = m0 >> 10;   // all 64 rows of this tile share b (1024 % 64 == 0)
#pragma unroll
    for (int ir = 0; ir < 4; ++ir) {
        int m = m0 + tr * 4 + ir;
        int t = m & (T_ - 1);
        float4 v = make_float4(acc[ir][0], acc[ir][1], acc[ir][2], acc[ir][3]);
        *(float4*)(qkv + (((size_t)p * BH_ + bq * H_ + h) * T_ + t) * D_ + tc * 4) = v;
    }
}

// ---------------------------------------------------------------------------
// Kernel 2: causal flash attention, fp32.
// One block per (b, h, 64-row q-tile): grid = 48 * 16 = 768, 256 threads.
// Qs: [d][r] transposed; KVs: K as [d][c], then reused for V as [c][d];
// Ps: [c][r] transposed. All rows padded to 68 floats (float4-aligned, bank-spread).
// Online softmax state (m, l) per row, replicated across the row's 16 lanes.
// ---------------------------------------------------------------------------
__global__ __launch_bounds__(256) void attn_kernel(
    const float* __restrict__ qkv,
    float* __restrict__ out)
{
    __shared__ float Qs[64][68];
    __shared__ float KVs[64][68];
    __shared__ float Ps[64][68];

    const int bid = blockIdx.x;
    const int qi = bid & 15;          // q-tile index 0..15
    const int bh = bid >> 4;          // 0..47
    const float* Q = qkv + (size_t)bh * T_ * D_;
    const float* K = qkv + (size_t)(BH_ + bh) * T_ * D_;
    const float* V = qkv + (size_t)(2 * BH_ + bh) * T_ * D_;

    const int tid = threadIdx.x;
    const int tr = tid >> 4, tc = tid & 15;

    // Load Q tile transposed: [d][r]
#pragma unroll
    for (int i = 0; i < 4; ++i) {
        int f = tid + 256 * i;        // 0..1023
        int r = f >> 4, dg = f & 15;
        float4 q4 = *(const float4*)(Q + (size_t)(qi * 64 + r) * D_ + dg * 4);
        Qs[dg * 4 + 0][r] = q4.x;
        Qs[dg * 4 + 1][r] = q4.y;
        Qs[dg * 4 + 2][r] = q4.z;
        Qs[dg * 4 + 3][r] = q4.w;
    }

    float o[4][4] = {};
    float mrow[4], lrow[4];
#pragma unroll
    for (int ir = 0; ir < 4; ++ir) { mrow[ir] = -INFINITY; lrow[ir] = 0.f; }

    for (int j = 0; j <= qi; ++j) {
        // K tile load, transposed [d][c]
#pragma unroll
        for (int i = 0; i < 4; ++i) {
            int f = tid + 256 * i;
            int r = f >> 4, dg = f & 15;
            float4 k4 = *(const float4*)(K + (size_t)(j * 64 + r) * D_ + dg * 4);
            KVs[dg * 4 + 0][r] = k4.x;
            KVs[dg * 4 + 1][r] = k4.y;
            KVs[dg * 4 + 2][r] = k4.z;
            KVs[dg * 4 + 3][r] = k4.w;
        }
        __syncthreads();   // K (and, first iter, Q) visible

        // GEMM1: S = Q K^T, thread owns rows 4tr..+3, cols 4tc..+3
        float s[4][4] = {};
#pragma unroll
        for (int kk = 0; kk < 64; ++kk) {
            float4 a4 = *(const float4*)(&Qs[kk][tr * 4]);
            float4 b4 = *(const float4*)(&KVs[kk][tc * 4]);
            float av[4] = {a4.x, a4.y, a4.z, a4.w};
            float bv[4] = {b4.x, b4.y, b4.z, b4.w};
#pragma unroll
            for (int ii = 0; ii < 4; ++ii)
#pragma unroll
                for (int jj = 0; jj < 4; ++jj)
                    s[ii][jj] = fmaf(av[ii], bv[jj], s[ii][jj]);
        }

        const float sc = 0.125f;  // D^-0.5
        if (j == qi) {
#pragma unroll
            for (int ii = 0; ii < 4; ++ii)
#pragma unroll
                for (int jj = 0; jj < 4; ++jj)
                    s[ii][jj] = (tc * 4 + jj <= tr * 4 + ii) ? s[ii][jj] * sc : -INFINITY;
        } else {
#pragma unroll
            for (int ii = 0; ii < 4; ++ii)
#pragma unroll
                for (int jj = 0; jj < 4; ++jj)
                    s[ii][jj] *= sc;
        }

        // Online softmax per row; row = 16 consecutive lanes (same tr), shuffle-reduce.
#pragma unroll
        for (int ir = 0; ir < 4; ++ir) {
            float mx = fmaxf(fmaxf(s[ir][0], s[ir][1]), fmaxf(s[ir][2], s[ir][3]));
#pragma unroll
            for (int w = 1; w < 16; w <<= 1)
                mx = fmaxf(mx, __shfl_xor(mx, w));
            float mnew = fmaxf(mrow[ir], mx);
            float corr = __expf(mrow[ir] - mnew);   // 0 when mrow == -inf
            float p[4];
            float rs = 0.f;
#pragma unroll
            for (int ic = 0; ic < 4; ++ic) { p[ic] = __expf(s[ir][ic] - mnew); rs += p[ic]; }
#pragma unroll
            for (int w = 1; w < 16; w <<= 1)
                rs += __shfl_xor(rs, w);
            lrow[ir] = lrow[ir] * corr + rs;
            mrow[ir] = mnew;
#pragma unroll
            for (int ic = 0; ic < 4; ++ic) {
                o[ir][ic] *= corr;
                Ps[tc * 4 + ic][tr * 4 + ir] = p[ic];   // transposed [c][r]
            }
        }
        __syncthreads();   // P visible; everyone done reading K from KVs

        // V tile load, direct [c][d]
#pragma unroll
        for (int i = 0; i < 4; ++i) {
            int f = tid + 256 * i;
            int c = f >> 4, dg = f & 15;
            *(float4*)(&KVs[c][dg * 4]) = *(const float4*)(V + (size_t)(j * 64 + c) * D_ + dg * 4);
        }
        __syncthreads();

        // GEMM2: O += P V
#pragma unroll
        for (int c = 0; c < 64; ++c) {
            float4 a4 = *(const float4*)(&Ps[c][tr * 4]);
            float4 b4 = *(const float4*)(&KVs[c][tc * 4]);
            float av[4] = {a4.x, a4.y, a4.z, a4.w};
            float bv[4] = {b4.x, b4.y, b4.z, b4.w};
#pragma unroll
            for (int ii = 0; ii < 4; ++ii)
#pragma unroll
                for (int jj = 0; jj < 4; ++jj)
                    o[ii][jj] = fmaf(av[ii], bv[jj], o[ii][jj]);
        }
        __syncthreads();   // done with KVs/Ps before next iteration overwrites
    }

    // Epilogue: normalize and store. out[b][t][h*64+d]
    const int b = bh / H_;
    const int h = bh - b * H_;
#pragma unroll
    for (int ir = 0; ir < 4; ++ir) {
        float rl = 1.0f / lrow[ir];
        int t = qi * 64 + tr * 4 + ir;
        float4 v = make_float4(o[ir][0] * rl, o[ir][1] * rl, o[ir][2] * rl, o[ir][3] * rl);
        *(float4*)(out + ((size_t)b * T_ + t) * (H_ * D_) + h * D_ + tc * 4) = v;
    }
}

extern "C" void kernel_launch(void* const* d_in, const int* in_sizes, int n_in,
                              void* d_out, int out_size, void* d_ws, size_t ws_size,
                              hipStream_t stream) {
    const float* x  = (const float*)d_in[0];
    const float* Wq = (const float*)d_in[1];
    const float* Wk = (const float*)d_in[2];
    const float* Wv = (const float*)d_in[3];
    float* qkv = (float*)d_ws;     // [3][48][1024][64] fp32 = 37.7 MB
    float* out = (float*)d_out;

    dim3 pgrid(36, 64);            // n-tiles x m-tiles
    proj_kernel<<<pgrid, 256, 0, stream>>>(x, Wq, Wk, Wv, qkv);

    attn_kernel<<<768, 256, 0, stream>>>(qkv, out);
}

// Round 11
// 183.393 us; speedup vs baseline: 3.3193x; 3.3193x over previous
//
#include <hip/hip_runtime.h>
#include <math.h>
#include <stdint.h>

constexpr int B_ = 4, T_ = 1024, C_ = 768, H_ = 12, D_ = 64;
constexpr int BH_ = B_ * H_;   // 48
constexpr int M_ = B_ * T_;    // 4096
constexpr int N_ = 3 * H_ * D_;// 2304

using f32x4 = __attribute__((ext_vector_type(4))) float;
using s16x8 = __attribute__((ext_vector_type(8))) short;

__device__ __forceinline__ unsigned short f2bf(float f) {
    union { float f; uint32_t u; } v; v.f = f;
    uint32_t u = v.u + 0x7fffu + ((v.u >> 16) & 1u);   // RNE
    return (unsigned short)(u >> 16);
}

// ---------------------------------------------------------------------------
// cast x [4096][768] fp32 -> bf16, straight elementwise (float4 -> bf16x4)
// ---------------------------------------------------------------------------
__global__ __launch_bounds__(256) void cast_x_kernel(
    const float* __restrict__ x, unsigned short* __restrict__ X16)
{
    int i = blockIdx.x * 256 + threadIdx.x;      // float4 index, 786432 total
    float4 v = ((const float4*)x)[i];
    ushort4 o;
    o.x = f2bf(v.x); o.y = f2bf(v.y); o.z = f2bf(v.z); o.w = f2bf(v.w);
    ((ushort4*)X16)[i] = o;
}

// ---------------------------------------------------------------------------
// cast+transpose W into fused Wt[n][k] bf16, n = (p*12+h)*64+d, k = c.
// One block per (head-panel hp, 64-wide c-tile): 36*12 = 432 blocks.
// R8 FIX: transpose-out was d=f>>2, cg=f&3 (128 phantom rows x 32 cols):
// OOB LDS reads (L[64..128)) -> undefined garbage -> NaN via inf-inf in QK^T,
// plus cross-panel Wt clobbering and cols 32..64 never written.
// Correct: d=f>>3 (64 rows), cg=f&7 (8 x uint4 = 64 cols).
// ---------------------------------------------------------------------------
__global__ __launch_bounds__(256) void cast_w_kernel(
    const float* __restrict__ Wq, const float* __restrict__ Wk,
    const float* __restrict__ Wv, unsigned short* __restrict__ Wt)
{
    __shared__ unsigned short L[64][72];         // [d][c], pad 72 keeps rows 16B-aligned
    const int hp = blockIdx.x / 12, ct = blockIdx.x % 12;
    const int p = hp / H_, h = hp % H_;
    const float* W = (p == 0 ? Wq : (p == 1 ? Wk : Wv)) + (size_t)h * C_ * D_ + (size_t)ct * 64 * D_;
    const int tid = threadIdx.x;
#pragma unroll
    for (int it = 0; it < 4; ++it) {
        int f = tid + it * 256;                  // 0..1023 float4s: 64 c-rows x 16
        int c = f >> 4, dg = f & 15;
        float4 v = ((const float4*)(W + (size_t)c * D_))[dg];
        L[dg * 4 + 0][c] = f2bf(v.x);
        L[dg * 4 + 1][c] = f2bf(v.y);
        L[dg * 4 + 2][c] = f2bf(v.z);
        L[dg * 4 + 3][c] = f2bf(v.w);
    }
    __syncthreads();
#pragma unroll
    for (int it = 0; it < 2; ++it) {
        int f = tid + it * 256;                  // 0..511: 64 d-rows x 8 chunks of 8 bf16
        int d = f >> 3, cg = f & 7;              // FIXED (was f>>2 / f&3)
        uint4 v = *(const uint4*)&L[d][cg * 8];
        *(uint4*)(Wt + (size_t)(hp * 64 + d) * C_ + ct * 64 + cg * 8) = v;
    }
}

// ---------------------------------------------------------------------------
// QKV projection GEMM, MFMA bf16: C[4096 x 2304] = X16 * Wt^T.
// 128x128x32 tiles, 256 threads = 4 waves, each wave a 64x64 sub-tile
// (4x4 frags of 16x16x32). Writes Q,K panels [bh][t][d]; V transposed [bh][d][t].
// ---------------------------------------------------------------------------
__global__ __launch_bounds__(256) void proj_kernel(
    const unsigned short* __restrict__ X16,
    const unsigned short* __restrict__ Wt,
    unsigned short* __restrict__ Qp,
    unsigned short* __restrict__ Kp,
    unsigned short* __restrict__ Vt)
{
    __shared__ unsigned short As[128 * 32];      // [m][k] linear, 64B rows
    __shared__ unsigned short Bs[128 * 32];      // [n][k] linear
    const int tid = threadIdx.x;
    const int l = tid & 63, w = tid >> 6;
    const int n0 = blockIdx.x * 128, m0 = blockIdx.y * 128;
    const int msub = (w >> 1) * 64, nsub = (w & 1) * 64;
    const int lr = l & 15, lg = l >> 4;

    f32x4 acc[4][4];
#pragma unroll
    for (int i = 0; i < 4; ++i)
#pragma unroll
        for (int j = 0; j < 4; ++j)
            acc[i][j] = (f32x4){0.f, 0.f, 0.f, 0.f};

    for (int k0 = 0; k0 < C_; k0 += 32) {
#pragma unroll
        for (int it = 0; it < 2; ++it) {
            int f = tid + it * 256;              // 512 16B-chunks per tile
            int m = f >> 2, kc = f & 3;
            uint4 va = *(const uint4*)(X16 + (size_t)(m0 + m) * C_ + k0 + kc * 8);
            *(uint4*)(As + f * 8) = va;
            uint4 vb = *(const uint4*)(Wt + (size_t)(n0 + m) * C_ + k0 + kc * 8);
            *(uint4*)(Bs + f * 8) = vb;
        }
        __syncthreads();
        s16x8 a[4], b[4];
#pragma unroll
        for (int i = 0; i < 4; ++i) {
            a[i] = *(const s16x8*)(As + (msub + i * 16 + lr) * 32 + lg * 8);
            b[i] = *(const s16x8*)(Bs + (nsub + i * 16 + lr) * 32 + lg * 8);
        }
#pragma unroll
        for (int i = 0; i < 4; ++i)
#pragma unroll
            for (int j = 0; j < 4; ++j)
                acc[i][j] = __builtin_amdgcn_mfma_f32_16x16x32_bf16(a[i], b[j], acc[i][j], 0, 0, 0);
        __syncthreads();
    }

    const int bq = m0 >> 10;                     // batch (128 | 1024)
#pragma unroll
    for (int j = 0; j < 4; ++j) {
        int n = n0 + nsub + j * 16 + lr;         // wave-uniform head per frag-col group
        int hp = n >> 6, d = n & 63;
        int p = hp / H_, hh = hp % H_;
        int bh = bq * H_ + hh;
#pragma unroll
        for (int i = 0; i < 4; ++i) {
            int tb = m0 + msub + i * 16 + lg * 4;
            int t = tb & (T_ - 1);
            if (p == 2) {                        // V transposed: 4 t-consecutive -> 8B store
                ushort4 pv;
                pv.x = f2bf(acc[i][j][0]); pv.y = f2bf(acc[i][j][1]);
                pv.z = f2bf(acc[i][j][2]); pv.w = f2bf(acc[i][j][3]);
                *(ushort4*)(Vt + ((size_t)bh * D_ + d) * T_ + t) = pv;
            } else {
                unsigned short* P = (p == 0 ? Qp : Kp) + (size_t)bh * T_ * D_ + d;
#pragma unroll
                for (int r = 0; r < 4; ++r)
                    P[(size_t)(t + r) * D_] = f2bf(acc[i][j][r]);
            }
        }
    }
}

// ---------------------------------------------------------------------------
// Causal flash attention, MFMA bf16, fp32 accum.
// 1 wave per block; wave handles q-tiles (pr, 63-pr) => uniform 17 kv-tiles.
// Q/K read [t][d]; V read transposed [d][t]; P transposed via 2.3KB LDS.
// Finite sentinel NEG=-30000 (no inf arithmetic anywhere) + __syncthreads()
// around the P-LDS write->vector-read (1-wave block: ~free).
// ---------------------------------------------------------------------------
__global__ __launch_bounds__(64) void attn_kernel(
    const unsigned short* __restrict__ Qp,
    const unsigned short* __restrict__ Kp,
    const unsigned short* __restrict__ Vt,
    float* __restrict__ out)
{
    __shared__ unsigned short Pl[16 * 72];       // [q][kv] padded to 72 (rows 16B-aligned)
    const int l = threadIdx.x;
    const int lr = l & 15, lg = l >> 4;
    const int bh = blockIdx.x >> 5, pr = blockIdx.x & 31;
    const int bq = bh / H_, hh = bh % H_;
    const unsigned short* Q = Qp + (size_t)bh * T_ * D_;
    const unsigned short* K = Kp + (size_t)bh * T_ * D_;
    const unsigned short* V = Vt + (size_t)bh * D_ * T_;
    float* O = out + (size_t)bq * T_ * (H_ * D_) + hh * D_;

    const float NEG = -30000.0f;                 // finite "-inf": exp(NEG-mn)==0

    for (int half = 0; half < 2; ++half) {
        const int qi = half ? (63 - pr) : pr;
        const int q0 = qi * 16;
        s16x8 qa0 = *(const s16x8*)(Q + (size_t)(q0 + lr) * D_ + lg * 8);
        s16x8 qa1 = *(const s16x8*)(Q + (size_t)(q0 + lr) * D_ + 32 + lg * 8);

        f32x4 o[4];
        float m[4], ll[4];
#pragma unroll
        for (int g = 0; g < 4; ++g) o[g] = (f32x4){0.f, 0.f, 0.f, 0.f};
#pragma unroll
        for (int r = 0; r < 4; ++r) { m[r] = NEG; ll[r] = 0.f; }

        const int ntile = (qi >> 2) + 1;
        for (int j = 0; j < ntile; ++j) {
            const int kv0 = j * 64;
            f32x4 s[4];
#pragma unroll
            for (int g = 0; g < 4; ++g) s[g] = (f32x4){0.f, 0.f, 0.f, 0.f};
#pragma unroll
            for (int g = 0; g < 4; ++g) {
                const unsigned short* kr = K + (size_t)(kv0 + g * 16 + lr) * D_ + lg * 8;
                s16x8 kb0 = *(const s16x8*)(kr);
                s16x8 kb1 = *(const s16x8*)(kr + 32);
                s[g] = __builtin_amdgcn_mfma_f32_16x16x32_bf16(qa0, kb0, s[g], 0, 0, 0);
                s[g] = __builtin_amdgcn_mfma_f32_16x16x32_bf16(qa1, kb1, s[g], 0, 0, 0);
            }
            const bool last = (j == ntile - 1);
            const float sc = 0.125f;             // D^-0.5
#pragma unroll
            for (int g = 0; g < 4; ++g)
#pragma unroll
                for (int r = 0; r < 4; ++r) {
                    float v = s[g][r] * sc;
                    if (last && (kv0 + g * 16 + lr > q0 + lg * 4 + r)) v = NEG;
                    s[g][r] = v;
                }
#pragma unroll
            for (int r = 0; r < 4; ++r) {
                float mx = fmaxf(fmaxf(s[0][r], s[1][r]), fmaxf(s[2][r], s[3][r]));
                mx = fmaxf(mx, __shfl_xor(mx, 1));
                mx = fmaxf(mx, __shfl_xor(mx, 2));
                mx = fmaxf(mx, __shfl_xor(mx, 4));
                mx = fmaxf(mx, __shfl_xor(mx, 8));
                float mn = fmaxf(m[r], mx);
                float corr = __expf(m[r] - mn);  // ==0 on first tile (NEG - mn)
                float p[4], rs = 0.f;
#pragma unroll
                for (int g = 0; g < 4; ++g) { p[g] = __expf(s[g][r] - mn); rs += p[g]; }
                rs += __shfl_xor(rs, 1); rs += __shfl_xor(rs, 2);
                rs += __shfl_xor(rs, 4); rs += __shfl_xor(rs, 8);
                ll[r] = ll[r] * corr + rs;
                m[r] = mn;
#pragma unroll
                for (int g = 0; g < 4; ++g) {
                    o[g][r] *= corr;
                    Pl[(lg * 4 + r) * 72 + g * 16 + lr] = f2bf(p[g]);
                }
            }
            __syncthreads();                     // order P writes before vector re-read

            // P A-frags (transposed read) + PV
            s16x8 pa0 = *(const s16x8*)(Pl + lr * 72 + lg * 8);
            s16x8 pa1 = *(const s16x8*)(Pl + lr * 72 + 32 + lg * 8);
#pragma unroll
            for (int g = 0; g < 4; ++g) {
                const unsigned short* vr = V + (size_t)(g * 16 + lr) * T_ + kv0 + lg * 8;
                s16x8 vb0 = *(const s16x8*)(vr);
                s16x8 vb1 = *(const s16x8*)(vr + 32);
                o[g] = __builtin_amdgcn_mfma_f32_16x16x32_bf16(pa0, vb0, o[g], 0, 0, 0);
                o[g] = __builtin_amdgcn_mfma_f32_16x16x32_bf16(pa1, vb1, o[g], 0, 0, 0);
            }
            __syncthreads();                     // P reads done before next-iter writes
        }
        float rinv[4];
#pragma unroll
        for (int r = 0; r < 4; ++r) rinv[r] = 1.0f / ll[r];
#pragma unroll
        for (int g = 0; g < 4; ++g)
#pragma unroll
            for (int r = 0; r < 4; ++r)
                O[(size_t)(q0 + lg * 4 + r) * (H_ * D_) + g * 16 + lr] = o[g][r] * rinv[r];
    }
}

extern "C" void kernel_launch(void* const* d_in, const int* in_sizes, int n_in,
                              void* d_out, int out_size, void* d_ws, size_t ws_size,
                              hipStream_t stream) {
    const float* x  = (const float*)d_in[0];
    const float* Wq = (const float*)d_in[1];
    const float* Wk = (const float*)d_in[2];
    const float* Wv = (const float*)d_in[3];
    float* out = (float*)d_out;

    char* ws = (char*)d_ws;
    unsigned short* X16 = (unsigned short*)(ws);                 // 6,291,456 B
    unsigned short* Wt  = (unsigned short*)(ws + 6291456);       // 3,538,944 B
    unsigned short* Qp  = (unsigned short*)(ws + 9830400);       // 6,291,456 B
    unsigned short* Kp  = (unsigned short*)(ws + 16121856);      // 6,291,456 B
    unsigned short* Vt  = (unsigned short*)(ws + 22413312);      // 6,291,456 B

    cast_x_kernel<<<(M_ * C_ / 4) / 256, 256, 0, stream>>>(x, X16);
    cast_w_kernel<<<36 * 12, 256, 0, stream>>>(Wq, Wk, Wv, Wt);
    proj_kernel<<<dim3(N_ / 128, M_ / 128), 256, 0, stream>>>(X16, Wt, Qp, Kp, Vt);
    attn_kernel<<<BH_ * 32, 64, 0, stream>>>(Qp, Kp, Vt, out);
}

// Round 12
// 182.716 us; speedup vs baseline: 3.3317x; 1.0037x over previous
//
#include <hip/hip_runtime.h>
#include <math.h>
#include <stdint.h>

constexpr int B_ = 4, T_ = 1024, C_ = 768, H_ = 12, D_ = 64;
constexpr int BH_ = B_ * H_;   // 48
constexpr int M_ = B_ * T_;    // 4096
constexpr int N_ = 3 * H_ * D_;// 2304

using f32x4 = __attribute__((ext_vector_type(4))) float;
using s16x8 = __attribute__((ext_vector_type(8))) short;

__device__ __forceinline__ unsigned short f2bf(float f) {
    union { float f; uint32_t u; } v; v.f = f;
    uint32_t u = v.u + 0x7fffu + ((v.u >> 16) & 1u);   // RNE
    return (unsigned short)(u >> 16);
}

// ---------------------------------------------------------------------------
// cast x [4096][768] fp32 -> bf16, straight elementwise (float4 -> bf16x4)
// ---------------------------------------------------------------------------
__global__ __launch_bounds__(256) void cast_x_kernel(
    const float* __restrict__ x, unsigned short* __restrict__ X16)
{
    int i = blockIdx.x * 256 + threadIdx.x;      // float4 index, 786432 total
    float4 v = ((const float4*)x)[i];
    ushort4 o;
    o.x = f2bf(v.x); o.y = f2bf(v.y); o.z = f2bf(v.z); o.w = f2bf(v.w);
    ((ushort4*)X16)[i] = o;
}

// ---------------------------------------------------------------------------
// cast+transpose W into fused Wt[n][k] bf16, n = (p*12+h)*64+d, k = c.
// One block per (head-panel hp, 64-wide c-tile): 36*12 = 432 blocks.
// ---------------------------------------------------------------------------
__global__ __launch_bounds__(256) void cast_w_kernel(
    const float* __restrict__ Wq, const float* __restrict__ Wk,
    const float* __restrict__ Wv, unsigned short* __restrict__ Wt)
{
    __shared__ unsigned short L[64][72];         // [d][c], pad 72 keeps rows 16B-aligned
    const int hp = blockIdx.x / 12, ct = blockIdx.x % 12;
    const int p = hp / H_, h = hp % H_;
    const float* W = (p == 0 ? Wq : (p == 1 ? Wk : Wv)) + (size_t)h * C_ * D_ + (size_t)ct * 64 * D_;
    const int tid = threadIdx.x;
#pragma unroll
    for (int it = 0; it < 4; ++it) {
        int f = tid + it * 256;                  // 0..1023 float4s: 64 c-rows x 16
        int c = f >> 4, dg = f & 15;
        float4 v = ((const float4*)(W + (size_t)c * D_))[dg];
        L[dg * 4 + 0][c] = f2bf(v.x);
        L[dg * 4 + 1][c] = f2bf(v.y);
        L[dg * 4 + 2][c] = f2bf(v.z);
        L[dg * 4 + 3][c] = f2bf(v.w);
    }
    __syncthreads();
#pragma unroll
    for (int it = 0; it < 2; ++it) {
        int f = tid + it * 256;                  // 0..511: 64 d-rows x 8 chunks of 8 bf16
        int d = f >> 3, cg = f & 7;
        uint4 v = *(const uint4*)&L[d][cg * 8];
        *(uint4*)(Wt + (size_t)(hp * 64 + d) * C_ + ct * 64 + cg * 8) = v;
    }
}

// ---------------------------------------------------------------------------
// QKV projection GEMM, MFMA bf16: C[4096 x 2304] = X16 * Wt^T.
// 128x128x32 tiles, 256 threads = 4 waves, each wave a 64x64 sub-tile
// (4x4 frags of 16x16x32). Writes Q,K panels [bh][t][d]; V transposed [bh][d][t].
// ---------------------------------------------------------------------------
__global__ __launch_bounds__(256) void proj_kernel(
    const unsigned short* __restrict__ X16,
    const unsigned short* __restrict__ Wt,
    unsigned short* __restrict__ Qp,
    unsigned short* __restrict__ Kp,
    unsigned short* __restrict__ Vt)
{
    __shared__ unsigned short As[128 * 32];      // [m][k] linear, 64B rows
    __shared__ unsigned short Bs[128 * 32];      // [n][k] linear
    const int tid = threadIdx.x;
    const int l = tid & 63, w = tid >> 6;
    const int n0 = blockIdx.x * 128, m0 = blockIdx.y * 128;
    const int msub = (w >> 1) * 64, nsub = (w & 1) * 64;
    const int lr = l & 15, lg = l >> 4;

    f32x4 acc[4][4];
#pragma unroll
    for (int i = 0; i < 4; ++i)
#pragma unroll
        for (int j = 0; j < 4; ++j)
            acc[i][j] = (f32x4){0.f, 0.f, 0.f, 0.f};

    for (int k0 = 0; k0 < C_; k0 += 32) {
#pragma unroll
        for (int it = 0; it < 2; ++it) {
            int f = tid + it * 256;              // 512 16B-chunks per tile
            int m = f >> 2, kc = f & 3;
            uint4 va = *(const uint4*)(X16 + (size_t)(m0 + m) * C_ + k0 + kc * 8);
            *(uint4*)(As + f * 8) = va;
            uint4 vb = *(const uint4*)(Wt + (size_t)(n0 + m) * C_ + k0 + kc * 8);
            *(uint4*)(Bs + f * 8) = vb;
        }
        __syncthreads();
        s16x8 a[4], b[4];
#pragma unroll
        for (int i = 0; i < 4; ++i) {
            a[i] = *(const s16x8*)(As + (msub + i * 16 + lr) * 32 + lg * 8);
            b[i] = *(const s16x8*)(Bs + (nsub + i * 16 + lr) * 32 + lg * 8);
        }
#pragma unroll
        for (int i = 0; i < 4; ++i)
#pragma unroll
            for (int j = 0; j < 4; ++j)
                acc[i][j] = __builtin_amdgcn_mfma_f32_16x16x32_bf16(a[i], b[j], acc[i][j], 0, 0, 0);
        __syncthreads();
    }

    const int bq = m0 >> 10;                     // batch (128 | 1024)
#pragma unroll
    for (int j = 0; j < 4; ++j) {
        int n = n0 + nsub + j * 16 + lr;         // wave-uniform head per frag-col group
        int hp = n >> 6, d = n & 63;
        int p = hp / H_, hh = hp % H_;
        int bh = bq * H_ + hh;
#pragma unroll
        for (int i = 0; i < 4; ++i) {
            int tb = m0 + msub + i * 16 + lg * 4;
            int t = tb & (T_ - 1);
            if (p == 2) {                        // V transposed: 4 t-consecutive -> 8B store
                ushort4 pv;
                pv.x = f2bf(acc[i][j][0]); pv.y = f2bf(acc[i][j][1]);
                pv.z = f2bf(acc[i][j][2]); pv.w = f2bf(acc[i][j][3]);
                *(ushort4*)(Vt + ((size_t)bh * D_ + d) * T_ + t) = pv;
            } else {
                unsigned short* P = (p == 0 ? Qp : Kp) + (size_t)bh * T_ * D_ + d;
#pragma unroll
                for (int r = 0; r < 4; ++r)
                    P[(size_t)(t + r) * D_] = f2bf(acc[i][j][r]);
            }
        }
    }
}

// ---------------------------------------------------------------------------
// Causal flash attention v2, MFMA bf16, fp32 accum.
// R11 changes (attn was 72us: Occ 15% = 1.5 waves/SIMD, MfmaUtil 3.5%,
// FETCH 154MB vs ~25MB compulsory -> latency-bound + L2 thrash):
//  1) UNPAIRED: one 16-row q-tile per wave -> 3072 waves = 3/SIMD (2x occ).
//  2) XCD swizzle: id = (bh&7) + 8*(qi + 64*(bh>>3)) -> all 64 q-tiles of a
//     head on one XCD; 6 heads x 256KB K/V = 1.5MB fits 4MB L2.
//  3) Batch K+V tile loads into registers BEFORE MFMAs: one load-latency per
//     tile instead of serialized; V-latency hides under QK+softmax.
//  __launch_bounds__(64,3) caps VGPR ~170 (est ~120) -> guaranteed 3/SIMD.
// ---------------------------------------------------------------------------
__global__ __launch_bounds__(64, 3) void attn_kernel(
    const unsigned short* __restrict__ Qp,
    const unsigned short* __restrict__ Kp,
    const unsigned short* __restrict__ Vt,
    float* __restrict__ out)
{
    __shared__ unsigned short Pl[16 * 72];       // [q][kv] padded to 72 (rows 16B-aligned)
    const int l = threadIdx.x;
    const int lr = l & 15, lg = l >> 4;
    const int id = blockIdx.x;                   // 0..3071, XCD-swizzled
    const int xcd = id & 7, rest = id >> 3;
    const int qi = rest & 63;                    // q-tile 0..63
    const int bh = xcd + 8 * (rest >> 6);        // 0..47 (bh&7 == xcd)
    const int bq = bh / H_, hh = bh % H_;
    const unsigned short* Q = Qp + (size_t)bh * T_ * D_;
    const unsigned short* K = Kp + (size_t)bh * T_ * D_;
    const unsigned short* V = Vt + (size_t)bh * D_ * T_;
    float* O = out + (size_t)bq * T_ * (H_ * D_) + hh * D_;

    const float NEG = -30000.0f;                 // finite "-inf": exp(NEG-mn)==0
    const int q0 = qi * 16;

    s16x8 qa0 = *(const s16x8*)(Q + (size_t)(q0 + lr) * D_ + lg * 8);
    s16x8 qa1 = *(const s16x8*)(Q + (size_t)(q0 + lr) * D_ + 32 + lg * 8);

    f32x4 o[4];
    float m[4], ll[4];
#pragma unroll
    for (int g = 0; g < 4; ++g) o[g] = (f32x4){0.f, 0.f, 0.f, 0.f};
#pragma unroll
    for (int r = 0; r < 4; ++r) { m[r] = NEG; ll[r] = 0.f; }

    const int ntile = (qi >> 2) + 1;
    for (int j = 0; j < ntile; ++j) {
        const int kv0 = j * 64;
        // ---- batch-issue ALL K and V loads for this tile (16 x dwordx4) ----
        s16x8 kb[8], vb[8];
#pragma unroll
        for (int g = 0; g < 4; ++g) {
            const unsigned short* kr = K + (size_t)(kv0 + g * 16 + lr) * D_ + lg * 8;
            kb[2 * g]     = *(const s16x8*)(kr);
            kb[2 * g + 1] = *(const s16x8*)(kr + 32);
        }
#pragma unroll
        for (int g = 0; g < 4; ++g) {
            const unsigned short* vr = V + (size_t)(g * 16 + lr) * T_ + kv0 + lg * 8;
            vb[2 * g]     = *(const s16x8*)(vr);
            vb[2 * g + 1] = *(const s16x8*)(vr + 32);
        }
        // ---- QK^T ----
        f32x4 s[4];
#pragma unroll
        for (int g = 0; g < 4; ++g) s[g] = (f32x4){0.f, 0.f, 0.f, 0.f};
#pragma unroll
        for (int g = 0; g < 4; ++g) {
            s[g] = __builtin_amdgcn_mfma_f32_16x16x32_bf16(qa0, kb[2 * g],     s[g], 0, 0, 0);
            s[g] = __builtin_amdgcn_mfma_f32_16x16x32_bf16(qa1, kb[2 * g + 1], s[g], 0, 0, 0);
        }
        const bool last = (j == ntile - 1);
        const float sc = 0.125f;                 // D^-0.5
#pragma unroll
        for (int g = 0; g < 4; ++g)
#pragma unroll
            for (int r = 0; r < 4; ++r) {
                float v = s[g][r] * sc;
                if (last && (kv0 + g * 16 + lr > q0 + lg * 4 + r)) v = NEG;
                s[g][r] = v;
            }
        // ---- online softmax (V loads still in flight) ----
#pragma unroll
        for (int r = 0; r < 4; ++r) {
            float mx = fmaxf(fmaxf(s[0][r], s[1][r]), fmaxf(s[2][r], s[3][r]));
            mx = fmaxf(mx, __shfl_xor(mx, 1));
            mx = fmaxf(mx, __shfl_xor(mx, 2));
            mx = fmaxf(mx, __shfl_xor(mx, 4));
            mx = fmaxf(mx, __shfl_xor(mx, 8));
            float mn = fmaxf(m[r], mx);
            float corr = __expf(m[r] - mn);      // ==0 on first tile
            float p[4], rs = 0.f;
#pragma unroll
            for (int g = 0; g < 4; ++g) { p[g] = __expf(s[g][r] - mn); rs += p[g]; }
            rs += __shfl_xor(rs, 1); rs += __shfl_xor(rs, 2);
            rs += __shfl_xor(rs, 4); rs += __shfl_xor(rs, 8);
            ll[r] = ll[r] * corr + rs;
            m[r] = mn;
#pragma unroll
            for (int g = 0; g < 4; ++g) {
                o[g][r] *= corr;
                Pl[(lg * 4 + r) * 72 + g * 16 + lr] = f2bf(p[g]);
            }
        }
        __syncthreads();                         // order P writes before vector re-read

        // ---- PV (V already in registers) ----
        s16x8 pa0 = *(const s16x8*)(Pl + lr * 72 + lg * 8);
        s16x8 pa1 = *(const s16x8*)(Pl + lr * 72 + 32 + lg * 8);
#pragma unroll
        for (int g = 0; g < 4; ++g) {
            o[g] = __builtin_amdgcn_mfma_f32_16x16x32_bf16(pa0, vb[2 * g],     o[g], 0, 0, 0);
            o[g] = __builtin_amdgcn_mfma_f32_16x16x32_bf16(pa1, vb[2 * g + 1], o[g], 0, 0, 0);
        }
        __syncthreads();                         // P reads done before next-iter writes
    }

    float rinv[4];
#pragma unroll
    for (int r = 0; r < 4; ++r) rinv[r] = 1.0f / ll[r];
#pragma unroll
    for (int g = 0; g < 4; ++g)
#pragma unroll
        for (int r = 0; r < 4; ++r)
            O[(size_t)(q0 + lg * 4 + r) * (H_ * D_) + g * 16 + lr] = o[g][r] * rinv[r];
}

extern "C" void kernel_launch(void* const* d_in, const int* in_sizes, int n_in,
                              void* d_out, int out_size, void* d_ws, size_t ws_size,
                              hipStream_t stream) {
    const float* x  = (const float*)d_in[0];
    const float* Wq = (const float*)d_in[1];
    const float* Wk = (const float*)d_in[2];
    const float* Wv = (const float*)d_in[3];
    float* out = (float*)d_out;

    char* ws = (char*)d_ws;
    unsigned short* X16 = (unsigned short*)(ws);                 // 6,291,456 B
    unsigned short* Wt  = (unsigned short*)(ws + 6291456);       // 3,538,944 B
    unsigned short* Qp  = (unsigned short*)(ws + 9830400);       // 6,291,456 B
    unsigned short* Kp  = (unsigned short*)(ws + 16121856);      // 6,291,456 B
    unsigned short* Vt  = (unsigned short*)(ws + 22413312);      // 6,291,456 B

    cast_x_kernel<<<(M_ * C_ / 4) / 256, 256, 0, stream>>>(x, X16);
    cast_w_kernel<<<36 * 12, 256, 0, stream>>>(Wq, Wk, Wv, Wt);
    proj_kernel<<<dim3(N_ / 128, M_ / 128), 256, 0, stream>>>(X16, Wt, Qp, Kp, Vt);
    attn_kernel<<<BH_ * 64, 64, 0, stream>>>(Qp, Kp, Vt, out);   // 3072 blocks, XCD-swizzled
}

// Round 13
// 181.177 us; speedup vs baseline: 3.3599x; 1.0085x over previous
//
#include <hip/hip_runtime.h>
#include <math.h>
#include <stdint.h>

constexpr int B_ = 4, T_ = 1024, C_ = 768, H_ = 12, D_ = 64;
constexpr int BH_ = B_ * H_;   // 48
constexpr int M_ = B_ * T_;    // 4096
constexpr int N_ = 3 * H_ * D_;// 2304

using f32x4 = __attribute__((ext_vector_type(4))) float;
using s16x8 = __attribute__((ext_vector_type(8))) short;

__device__ __forceinline__ unsigned short f2bf(float f) {
    union { float f; uint32_t u; } v; v.f = f;
    uint32_t u = v.u + 0x7fffu + ((v.u >> 16) & 1u);   // RNE
    return (unsigned short)(u >> 16);
}

// ---------------------------------------------------------------------------
// cast x [4096][768] fp32 -> bf16, straight elementwise (float4 -> bf16x4)
// ---------------------------------------------------------------------------
__global__ __launch_bounds__(256) void cast_x_kernel(
    const float* __restrict__ x, unsigned short* __restrict__ X16)
{
    int i = blockIdx.x * 256 + threadIdx.x;      // float4 index, 786432 total
    float4 v = ((const float4*)x)[i];
    ushort4 o;
    o.x = f2bf(v.x); o.y = f2bf(v.y); o.z = f2bf(v.z); o.w = f2bf(v.w);
    ((ushort4*)X16)[i] = o;
}

// ---------------------------------------------------------------------------
// cast+transpose W into fused Wt[n][k] bf16, n = (p*12+h)*64+d, k = c.
// One block per (head-panel hp, 64-wide c-tile): 36*12 = 432 blocks.
// ---------------------------------------------------------------------------
__global__ __launch_bounds__(256) void cast_w_kernel(
    const float* __restrict__ Wq, const float* __restrict__ Wk,
    const float* __restrict__ Wv, unsigned short* __restrict__ Wt)
{
    __shared__ unsigned short L[64][72];         // [d][c], pad 72 keeps rows 16B-aligned
    const int hp = blockIdx.x / 12, ct = blockIdx.x % 12;
    const int p = hp / H_, h = hp % H_;
    const float* W = (p == 0 ? Wq : (p == 1 ? Wk : Wv)) + (size_t)h * C_ * D_ + (size_t)ct * 64 * D_;
    const int tid = threadIdx.x;
#pragma unroll
    for (int it = 0; it < 4; ++it) {
        int f = tid + it * 256;                  // 0..1023 float4s: 64 c-rows x 16
        int c = f >> 4, dg = f & 15;
        float4 v = ((const float4*)(W + (size_t)c * D_))[dg];
        L[dg * 4 + 0][c] = f2bf(v.x);
        L[dg * 4 + 1][c] = f2bf(v.y);
        L[dg * 4 + 2][c] = f2bf(v.z);
        L[dg * 4 + 3][c] = f2bf(v.w);
    }
    __syncthreads();
#pragma unroll
    for (int it = 0; it < 2; ++it) {
        int f = tid + it * 256;                  // 0..511: 64 d-rows x 8 chunks of 8 bf16
        int d = f >> 3, cg = f & 7;
        uint4 v = *(const uint4*)&L[d][cg * 8];
        *(uint4*)(Wt + (size_t)(hp * 64 + d) * C_ + ct * 64 + cg * 8) = v;
    }
}

// ---------------------------------------------------------------------------
// QKV projection GEMM, MFMA bf16: C[4096 x 2304] = X16 * Wt^T.
// 128x128x32 tiles, 256 threads = 4 waves, each wave a 64x64 sub-tile
// (4x4 frags of 16x16x32). Writes Q,K panels [bh][t][d]; V transposed [bh][d][t].
// ---------------------------------------------------------------------------
__global__ __launch_bounds__(256) void proj_kernel(
    const unsigned short* __restrict__ X16,
    const unsigned short* __restrict__ Wt,
    unsigned short* __restrict__ Qp,
    unsigned short* __restrict__ Kp,
    unsigned short* __restrict__ Vt)
{
    __shared__ unsigned short As[128 * 32];      // [m][k] linear, 64B rows
    __shared__ unsigned short Bs[128 * 32];      // [n][k] linear
    const int tid = threadIdx.x;
    const int l = tid & 63, w = tid >> 6;
    const int n0 = blockIdx.x * 128, m0 = blockIdx.y * 128;
    const int msub = (w >> 1) * 64, nsub = (w & 1) * 64;
    const int lr = l & 15, lg = l >> 4;

    f32x4 acc[4][4];
#pragma unroll
    for (int i = 0; i < 4; ++i)
#pragma unroll
        for (int j = 0; j < 4; ++j)
            acc[i][j] = (f32x4){0.f, 0.f, 0.f, 0.f};

    for (int k0 = 0; k0 < C_; k0 += 32) {
#pragma unroll
        for (int it = 0; it < 2; ++it) {
            int f = tid + it * 256;              // 512 16B-chunks per tile
            int m = f >> 2, kc = f & 3;
            uint4 va = *(const uint4*)(X16 + (size_t)(m0 + m) * C_ + k0 + kc * 8);
            *(uint4*)(As + f * 8) = va;
            uint4 vb = *(const uint4*)(Wt + (size_t)(n0 + m) * C_ + k0 + kc * 8);
            *(uint4*)(Bs + f * 8) = vb;
        }
        __syncthreads();
        s16x8 a[4], b[4];
#pragma unroll
        for (int i = 0; i < 4; ++i) {
            a[i] = *(const s16x8*)(As + (msub + i * 16 + lr) * 32 + lg * 8);
            b[i] = *(const s16x8*)(Bs + (nsub + i * 16 + lr) * 32 + lg * 8);
        }
#pragma unroll
        for (int i = 0; i < 4; ++i)
#pragma unroll
            for (int j = 0; j < 4; ++j)
                acc[i][j] = __builtin_amdgcn_mfma_f32_16x16x32_bf16(a[i], b[j], acc[i][j], 0, 0, 0);
        __syncthreads();
    }

    const int bq = m0 >> 10;                     // batch (128 | 1024)
#pragma unroll
    for (int j = 0; j < 4; ++j) {
        int n = n0 + nsub + j * 16 + lr;         // wave-uniform head per frag-col group
        int hp = n >> 6, d = n & 63;
        int p = hp / H_, hh = hp % H_;
        int bh = bq * H_ + hh;
#pragma unroll
        for (int i = 0; i < 4; ++i) {
            int tb = m0 + msub + i * 16 + lg * 4;
            int t = tb & (T_ - 1);
            if (p == 2) {                        // V transposed: 4 t-consecutive -> 8B store
                ushort4 pv;
                pv.x = f2bf(acc[i][j][0]); pv.y = f2bf(acc[i][j][1]);
                pv.z = f2bf(acc[i][j][2]); pv.w = f2bf(acc[i][j][3]);
                *(ushort4*)(Vt + ((size_t)bh * D_ + d) * T_ + t) = pv;
            } else {
                unsigned short* P = (p == 0 ? Qp : Kp) + (size_t)bh * T_ * D_ + d;
#pragma unroll
                for (int r = 0; r < 4; ++r)
                    P[(size_t)(t + r) * D_] = f2bf(acc[i][j][r]);
            }
        }
    }
}

// ---------------------------------------------------------------------------
// Causal flash attention v3: SWAPPED-OPERAND MFMA (q = lane&15 everywhere).
// R12 post-mortem: 72us regardless of memory behavior; ~9000 cy/wave/tile ->
// latency chains. Old layout put each q-row across 16 lanes => 32 dependent
// shuffles/tile (LDS-pipe, ~100cy each). v3:
//   S^T = mfma(K,Q): C row=kv, col=q=lr -> lane owns a FULL q-row in regs.
//   Softmax: 15 in-lane fmax + 2 shfl (xor16,32); m,l are SCALARS.
//   O^T = mfma(V,P): C row=d, col=q=lr -> scalar corr/l rescale, no bcast.
//   P via LDS (double-buffered) -> ONE barrier/tile (was 2).
//   setprio(1) around MFMA clusters (T5: +4-7% on 1-wave attn blocks).
// Shuffles/tile: 32 -> 2.
// ---------------------------------------------------------------------------
__global__ __launch_bounds__(64, 3) void attn_kernel(
    const unsigned short* __restrict__ Qp,
    const unsigned short* __restrict__ Kp,
    const unsigned short* __restrict__ Vt,
    float* __restrict__ out)
{
    __shared__ unsigned short Pl[2][16 * 72];    // [q][kv] dbuf, rows 16B-aligned
    const int l = threadIdx.x;
    const int lr = l & 15, lg = l >> 4;
    const int id = blockIdx.x;                   // 0..3071, XCD-swizzled
    const int xcd = id & 7, rest = id >> 3;
    const int qi = rest & 63;                    // q-tile 0..63
    const int bh = xcd + 8 * (rest >> 6);        // 0..47 (bh&7 == xcd)
    const int bq = bh / H_, hh = bh % H_;
    const unsigned short* Q = Qp + (size_t)bh * T_ * D_;
    const unsigned short* K = Kp + (size_t)bh * T_ * D_;
    const unsigned short* V = Vt + (size_t)bh * D_ * T_;
    float* O = out + (size_t)bq * T_ * (H_ * D_) + hh * D_;

    const float NEG = -30000.0f;                 // finite "-inf"
    const int q0 = qi * 16;

    // Q fragment: lane holds Q[q0+lr][d = lg*8..+7] (B-operand for QK, col=q)
    s16x8 qa0 = *(const s16x8*)(Q + (size_t)(q0 + lr) * D_ + lg * 8);
    s16x8 qa1 = *(const s16x8*)(Q + (size_t)(q0 + lr) * D_ + 32 + lg * 8);

    f32x4 o[4];                                  // O^T acc: row=d (g*16+lg*4+r), col=q=lr
#pragma unroll
    for (int g = 0; g < 4; ++g) o[g] = (f32x4){0.f, 0.f, 0.f, 0.f};
    float m = NEG, ll = 0.f;                     // scalars: this lane's q-row = q0+lr

    const int ntile = (qi >> 2) + 1;
    for (int j = 0; j < ntile; ++j) {
        const int kv0 = j * 64;
        s16x8 kb[8], vb[8];
#pragma unroll
        for (int g = 0; g < 4; ++g) {
            const unsigned short* kr = K + (size_t)(kv0 + g * 16 + lr) * D_ + lg * 8;
            kb[2 * g]     = *(const s16x8*)(kr);
            kb[2 * g + 1] = *(const s16x8*)(kr + 32);
        }
#pragma unroll
        for (int g = 0; g < 4; ++g) {
            const unsigned short* vr = V + (size_t)(g * 16 + lr) * T_ + kv0 + lg * 8;
            vb[2 * g]     = *(const s16x8*)(vr);
            vb[2 * g + 1] = *(const s16x8*)(vr + 32);
        }
        // ---- S^T = K Q^T : s[g] row=kv (g*16+lg*4+r), col=q (lr) ----
        f32x4 s[4];
#pragma unroll
        for (int g = 0; g < 4; ++g) s[g] = (f32x4){0.f, 0.f, 0.f, 0.f};
        __builtin_amdgcn_s_setprio(1);
#pragma unroll
        for (int g = 0; g < 4; ++g) {
            s[g] = __builtin_amdgcn_mfma_f32_16x16x32_bf16(kb[2 * g],     qa0, s[g], 0, 0, 0);
            s[g] = __builtin_amdgcn_mfma_f32_16x16x32_bf16(kb[2 * g + 1], qa1, s[g], 0, 0, 0);
        }
        __builtin_amdgcn_s_setprio(0);
        const bool last = (j == ntile - 1);
        const float sc = 0.125f;                 // D^-0.5
#pragma unroll
        for (int g = 0; g < 4; ++g)
#pragma unroll
            for (int r = 0; r < 4; ++r) {
                float v = s[g][r] * sc;
                if (last && (kv0 + g * 16 + lg * 4 + r > q0 + lr)) v = NEG;
                s[g][r] = v;
            }
        // ---- softmax: lane owns q-row q0+lr; 16 in-lane vals + 2 shfl ----
        float m0 = fmaxf(fmaxf(s[0][0], s[0][1]), fmaxf(s[0][2], s[0][3]));
        float m1 = fmaxf(fmaxf(s[1][0], s[1][1]), fmaxf(s[1][2], s[1][3]));
        float m2 = fmaxf(fmaxf(s[2][0], s[2][1]), fmaxf(s[2][2], s[2][3]));
        float m3 = fmaxf(fmaxf(s[3][0], s[3][1]), fmaxf(s[3][2], s[3][3]));
        float mx = fmaxf(fmaxf(m0, m1), fmaxf(m2, m3));
        mx = fmaxf(mx, __shfl_xor(mx, 16));
        mx = fmaxf(mx, __shfl_xor(mx, 32));
        float mn = fmaxf(m, mx);
        float corr = __expf(m - mn);             // ==0 on first tile
        float rs = 0.f;
#pragma unroll
        for (int g = 0; g < 4; ++g)
#pragma unroll
            for (int r = 0; r < 4; ++r) {
                s[g][r] = __expf(s[g][r] - mn);
                rs += s[g][r];
            }
        rs += __shfl_xor(rs, 16);
        rs += __shfl_xor(rs, 32);
        ll = ll * corr + rs;
        m = mn;
#pragma unroll
        for (int g = 0; g < 4; ++g)
#pragma unroll
            for (int r = 0; r < 4; ++r)
                o[g][r] *= corr;
        // ---- P -> LDS (row q=lr), dbuf; one barrier ----
        unsigned short* pb = Pl[j & 1];
#pragma unroll
        for (int g = 0; g < 4; ++g)
#pragma unroll
            for (int r = 0; r < 4; ++r)
                pb[lr * 72 + g * 16 + lg * 4 + r] = f2bf(s[g][r]);
        __syncthreads();
        s16x8 pa0 = *(const s16x8*)(pb + lr * 72 + lg * 8);        // P[q=lr][kv 0..31]
        s16x8 pa1 = *(const s16x8*)(pb + lr * 72 + 32 + lg * 8);   // P[q=lr][kv 32..63]
        // ---- O^T += V^T P^T : A=vb (row=d), B=pa (col=q) ----
        __builtin_amdgcn_s_setprio(1);
#pragma unroll
        for (int g = 0; g < 4; ++g) {
            o[g] = __builtin_amdgcn_mfma_f32_16x16x32_bf16(vb[2 * g],     pa0, o[g], 0, 0, 0);
            o[g] = __builtin_amdgcn_mfma_f32_16x16x32_bf16(vb[2 * g + 1], pa1, o[g], 0, 0, 0);
        }
        __builtin_amdgcn_s_setprio(0);
        // no second barrier: next tile writes the other Pl buffer
    }

    const float rinv = 1.0f / ll;                // scalar: lane's q-row
#pragma unroll
    for (int g = 0; g < 4; ++g) {
        float4 v = make_float4(o[g][0] * rinv, o[g][1] * rinv,
                               o[g][2] * rinv, o[g][3] * rinv);
        *(float4*)(O + (size_t)(q0 + lr) * (H_ * D_) + g * 16 + lg * 4) = v;
    }
}

extern "C" void kernel_launch(void* const* d_in, const int* in_sizes, int n_in,
                              void* d_out, int out_size, void* d_ws, size_t ws_size,
                              hipStream_t stream) {
    const float* x  = (const float*)d_in[0];
    const float* Wq = (const float*)d_in[1];
    const float* Wk = (const float*)d_in[2];
    const float* Wv = (const float*)d_in[3];
    float* out = (float*)d_out;

    char* ws = (char*)d_ws;
    unsigned short* X16 = (unsigned short*)(ws);                 // 6,291,456 B
    unsigned short* Wt  = (unsigned short*)(ws + 6291456);       // 3,538,944 B
    unsigned short* Qp  = (unsigned short*)(ws + 9830400);       // 6,291,456 B
    unsigned short* Kp  = (unsigned short*)(ws + 16121856);      // 6,291,456 B
    unsigned short* Vt  = (unsigned short*)(ws + 22413312);      // 6,291,456 B

    cast_x_kernel<<<(M_ * C_ / 4) / 256, 256, 0, stream>>>(x, X16);
    cast_w_kernel<<<36 * 12, 256, 0, stream>>>(Wq, Wk, Wv, Wt);
    proj_kernel<<<dim3(N_ / 128, M_ / 128), 256, 0, stream>>>(X16, Wt, Qp, Kp, Vt);
    attn_kernel<<<BH_ * 64, 64, 0, stream>>>(Qp, Kp, Vt, out);   // 3072 blocks, XCD-swizzled
}